// Round 12
// baseline (627.889 us; speedup 1.0000x reference)
//
#include <hip/hip_runtime.h>
#include <hip/hip_bf16.h>

// Problem constants: T=8192, H=1024, D=1024, E=8, 2D=2048, K2=E*D=8192
#define T_DIM 8192
#define H_DIM 1024
#define D_DIM 1024
#define E_DIM 8
#define TWO_D 2048
#define K2 8192

#define ALPHA_C 1.702f
#define LIMIT_C 7.0f

typedef __attribute__((ext_vector_type(8))) short s8v;   // 8 bf16 = 4 VGPRs
typedef __attribute__((ext_vector_type(4))) float f4v;   // MFMA accumulator

__device__ __forceinline__ void g2l16(const void* g, void* l) {
    // async global->LDS, 16B per lane; LDS dest = wave-uniform base + lane*16
    __builtin_amdgcn_global_load_lds((const __attribute__((address_space(1))) void*)g,
                                     (__attribute__((address_space(3))) void*)l, 16, 0, 0);
}

__device__ __forceinline__ unsigned short f2bf(float f) {
    __hip_bfloat16 h = __float2bfloat16(f);
    return __builtin_bit_cast(unsigned short, h);
}

__device__ __forceinline__ float bf2f(unsigned short u) {
    unsigned int x = ((unsigned int)u) << 16;
    return __builtin_bit_cast(float, x);
}

// ---------------- convert kernels ----------------

__global__ void f32_to_bf16_kernel(const float* __restrict__ in,
                                   unsigned short* __restrict__ out, size_t n) {
    size_t i = ((size_t)blockIdx.x * blockDim.x + threadIdx.x) * 4;
    if (i + 3 < n) {
        float4 v = *(const float4*)(in + i);
        ushort4 o;
        o.x = f2bf(v.x); o.y = f2bf(v.y); o.z = f2bf(v.z); o.w = f2bf(v.w);
        *(ushort4*)(out + i) = o;
    }
}

// W1 [E][H][2D] -> w1b [E][2D'][H] bf16 with gate/up 16-col deinterleave.
// out[b*obs + remap(c)*ors + r] = bf16(in[b*ibs + r*cols + c]); 32x32 tiles.
__global__ void transpose_conv_kernel(const float* __restrict__ in,
                                      unsigned short* __restrict__ out,
                                      int cols, size_t ibs, size_t obs, size_t ors,
                                      int remap) {
    __shared__ float t[32][33];
    const int b = blockIdx.z;
    const int c0 = blockIdx.x * 32, r0 = blockIdx.y * 32;
    const int tx = threadIdx.x & 31, ty = threadIdx.x >> 5;  // ty in 0..7
    const float* ip = in + (size_t)b * ibs;
    #pragma unroll
    for (int i = 0; i < 4; ++i)
        t[ty + i * 8][tx] = ip[(size_t)(r0 + ty + i * 8) * cols + c0 + tx];
    __syncthreads();
    unsigned short* op = out + (size_t)b * obs;
    #pragma unroll
    for (int i = 0; i < 4; ++i) {
        int c = c0 + ty + i * 8;
        int nc = remap ? ((c & ~31) + ((c & 1) << 4) + ((c >> 1) & 15)) : c;
        op[(size_t)nc * ors + r0 + tx] = f2bf(t[tx][ty + i * 8]);
    }
}

// W3 [E][D][H] -> w3t tiled bf16: tile (nt, kt) = [128 H-rows][64 k-elems], laid out
// at ((nt*128 + kt)*8192), with XOR chunk swizzle baked in: element (hcol, k) goes to
// tile offset (hcol&127)*64 + ((k&63) ^ ((hcol&7)<<3)).  k = e*1024 + d.
__global__ void transpose_w3_tiled_kernel(const float* __restrict__ in,
                                          unsigned short* __restrict__ out) {
    __shared__ float t[32][33];
    const int e = blockIdx.z;
    const int c0 = blockIdx.x * 32;   // H cols
    const int r0 = blockIdx.y * 32;   // D rows
    const int tx = threadIdx.x & 31, ty = threadIdx.x >> 5;
    const float* ip = in + (size_t)e * D_DIM * H_DIM;
    #pragma unroll
    for (int i = 0; i < 4; ++i)
        t[ty + i * 8][tx] = ip[(size_t)(r0 + ty + i * 8) * H_DIM + c0 + tx];
    __syncthreads();
    #pragma unroll
    for (int i = 0; i < 4; ++i) {
        const int hcol = c0 + ty + i * 8;
        const int kk = e * D_DIM + r0 + tx;
        const int nt = hcol >> 7, rIn = hcol & 127;
        const int kt = kk >> 6, c = kk & 63;
        out[((size_t)nt * 128 + kt) * 8192 + rIn * 64 + (c ^ ((rIn & 7) << 3))] =
            f2bf(t[tx][ty + i * 8]);
    }
}

// out[t][h] += p0 (bf16 partial from gemm2 ks=1); bias already fused in gemm2 ks=0.
__global__ void reduce_kernel(const unsigned short* __restrict__ p0,
                              float* __restrict__ out) {
    const int t = blockIdx.x;
    const int h = threadIdx.x * 4;
    const size_t idx = (size_t)t * H_DIM + h;
    float4 v = *(const float4*)(out + idx);
    ushort4 a = *(const ushort4*)(p0 + idx);
    v.x += bf2f(a.x);
    v.y += bf2f(a.y);
    v.z += bf2f(a.z);
    v.w += bf2f(a.w);
    *(float4*)(out + idx) = v;
}

// ---------------- GEMM1 (proven config: 259-270 µs, MfmaUtil ~51) ----------------
// 128x128 tile, BK=64, 4 waves, single-buffer 32 KB, ~3 blocks/CU.
// gu = hs @ W1[e] + b1[e]; act2 = rw*(up+1)*glu, written TILED+swizzled (act2t).
// A: hsb [T][H] bf16. B: w1b [E][2D'][H] bf16 (deinterleaved B^T).
// Grid (x=m fastest, y=n, z=e): 8 consecutive blocks (8 XCDs) share one B n-tile.

__global__ __launch_bounds__(256, 2) void gemm1_kernel(
    const short* __restrict__ Ag0,      // hsb
    const short* __restrict__ Bg0,      // w1b
    const float* __restrict__ b1,       // [E][2D] original interleaved
    const float* __restrict__ rw,       // [T][E]
    unsigned short* __restrict__ act2t) // tiled [64][128][128][64]
{
    const int e = blockIdx.z;
    const int mBase = blockIdx.x * 128;
    const int nBase = blockIdx.y * 128;
    const int tid = threadIdx.x;
    const int lane = tid & 63;
    const int wave = tid >> 6;
    const int wm = wave >> 1, wn = wave & 1;
    const int cq = lane & 15, quad = lane >> 4;

    __shared__ __align__(16) short As[128 * 64];
    __shared__ __align__(16) short Bs[128 * 64];

    const short* Ag = Ag0 + (size_t)mBase * H_DIM;
    const short* Bg = Bg0 + ((size_t)e * TWO_D + nBase) * H_DIM;

    f4v acc[4][4];
    #pragma unroll
    for (int mt = 0; mt < 4; ++mt)
        #pragma unroll
        for (int nt = 0; nt < 4; ++nt)
            acc[mt][nt] = (f4v){0.f, 0.f, 0.f, 0.f};

    const int srow8 = lane >> 3;                 // 0..7
    const int gco = ((lane & 7) ^ srow8) * 8;    // swizzled global k-offset (elements)
    const int cq7 = cq & 7;

    for (int k0 = 0; k0 < H_DIM; k0 += 64) {
        #pragma unroll
        for (int i = 0; i < 4; ++i) {
            const int r = wave * 32 + i * 8 + srow8;
            g2l16(Ag + (size_t)r * H_DIM + k0 + gco, As + (wave * 32 + i * 8) * 64);
            g2l16(Bg + (size_t)r * H_DIM + k0 + gco, Bs + (wave * 32 + i * 8) * 64);
        }
        __syncthreads();
        #pragma unroll
        for (int h = 0; h < 2; ++h) {
            s8v af[4], bf[4];
            const int pc = (((h << 2) + quad) ^ cq7) * 8;  // phys chunk offset (elements)
            #pragma unroll
            for (int i = 0; i < 4; ++i) {
                af[i] = *(const s8v*)(As + (wm * 64 + i * 16 + cq) * 64 + pc);
                bf[i] = *(const s8v*)(Bs + (wn * 64 + i * 16 + cq) * 64 + pc);
            }
            #pragma unroll
            for (int mt = 0; mt < 4; ++mt)
                #pragma unroll
                for (int nt = 0; nt < 4; ++nt)
                    acc[mt][nt] = __builtin_amdgcn_mfma_f32_16x16x32_bf16(
                        af[mt], bf[nt], acc[mt][nt], 0, 0, 0);
        }
        __syncthreads();
    }

    // epilogue: even nt tile = gate, odd nt tile = up for the same D-cols.
    float rwv[4][4];
    #pragma unroll
    for (int mt = 0; mt < 4; ++mt)
        #pragma unroll
        for (int r = 0; r < 4; ++r)
            rwv[mt][r] = rw[(size_t)(mBase + wm * 64 + mt * 16 + quad * 4 + r) * E_DIM + e];

    const int kt_blk = e * 16 + blockIdx.y;
    unsigned short* tb = act2t + ((size_t)blockIdx.x * 128 + kt_blk) * 8192;

    #pragma unroll
    for (int p = 0; p < 2; ++p) {
        const int j = (((nBase + wn * 64 + p * 32) >> 5) << 4) + cq;   // D-col in [0,1024)
        const float gb = b1[(size_t)e * TWO_D + 2 * j];
        const float ub = b1[(size_t)e * TWO_D + 2 * j + 1];
        const int c = wn * 32 + p * 16 + cq;                           // j & 63
        #pragma unroll
        for (int mt = 0; mt < 4; ++mt) {
            #pragma unroll
            for (int r = 0; r < 4; ++r) {
                float gate = acc[mt][2 * p][r] + gb;
                float up   = acc[mt][2 * p + 1][r] + ub;
                gate = fminf(gate, LIMIT_C);
                up = fminf(fmaxf(up, -LIMIT_C), LIMIT_C);
                float glu = gate / (1.f + __expf(-ALPHA_C * gate));
                float a = (up + 1.f) * glu * rwv[mt][r];
                const int rIn = wm * 64 + mt * 16 + quad * 4 + r;      // row within tile
                tb[rIn * 64 + (c ^ ((rIn & 7) << 3))] = f2bf(a);
            }
        }
    }
}

// ---------------- GEMM2 (r9 proven core): 256x128, split-K=2, tiled operands -----
// out_partial = act2 @ w3^T. A: act2t tiled [64][128][128][64] bf16 (XOR baked).
// B: w3t tiled [8][128][128][64] bf16. Grid 512 = 32m x 8n x 2ks = 2 blocks/CU.
// id: m = id&31 (8 n-sharers of an A panel have same id%8 -> same XCD L2),
// n = (id>>5)&7, ks = id>>8 (K-slice of 4096 = 64 BK steps).
// Staging fully contiguous: each g2l16 = 1 KB (8 rows x 64 elems) at src+lane*16B.
// ks0 -> out (f32, routed bias FUSED); ks1 -> p0 (bf16 partial, proven-safe r0);
// reduce adds p0 into out.

__global__ __launch_bounds__(256, 2) void gemm2_kernel(
    const short* __restrict__ At,      // act2t
    const short* __restrict__ Bt,      // w3t
    const float* __restrict__ rw,      // [T][E]
    const float* __restrict__ b3,      // [E][H]
    float* __restrict__ out,           // [T][H] acc+bias (ks=0)
    unsigned short* __restrict__ p0)   // [T][H] bf16 partial (ks=1)
{
    const int id = blockIdx.x;
    const int mIdx = id & 31;
    const int nIdx = (id >> 5) & 7;
    const int ks = id >> 8;
    const int tid = threadIdx.x;
    const int lane = tid & 63;
    const int wave = tid >> 6;           // 0..3
    const int wm = wave >> 1, wn = wave & 1;
    const int cq = lane & 15, quad = lane >> 4;
    const int cq7 = cq & 7;
    const int lane8 = lane * 8;

    __shared__ __align__(16) short As[256 * 64];   // 32 KiB
    __shared__ __align__(16) short Bs[128 * 64];   // 16 KiB

    f4v acc[8][4];
    #pragma unroll
    for (int mt = 0; mt < 8; ++mt)
        #pragma unroll
        for (int nt = 0; nt < 4; ++nt)
            acc[mt][nt] = (f4v){0.f, 0.f, 0.f, 0.f};

    #pragma unroll 1
    for (int s = 0; s < 64; ++s) {
        const int kt = ks * 64 + s;
        #pragma unroll
        for (int i = 0; i < 8; ++i) {
            const int R = i * 32 + wave * 8;
            const short* src = At +
                ((size_t)(2 * mIdx + (R >> 7)) * 128 + kt) * 8192 + (R & 127) * 64 + lane8;
            g2l16(src, As + R * 64);
        }
        #pragma unroll
        for (int i = 0; i < 4; ++i) {
            const int R = i * 32 + wave * 8;
            const short* src = Bt + ((size_t)nIdx * 128 + kt) * 8192 + R * 64 + lane8;
            g2l16(src, Bs + R * 64);
        }
        __syncthreads();
        #pragma unroll
        for (int h = 0; h < 2; ++h) {
            const int pc = (((h << 2) + quad) ^ cq7) * 8;
            s8v bf[4];
            #pragma unroll
            for (int i = 0; i < 4; ++i)
                bf[i] = *(const s8v*)(Bs + (wn * 64 + i * 16 + cq) * 64 + pc);
            #pragma unroll
            for (int mt = 0; mt < 8; ++mt) {
                const s8v af = *(const s8v*)(As + (wm * 128 + mt * 16 + cq) * 64 + pc);
                #pragma unroll
                for (int nt = 0; nt < 4; ++nt)
                    acc[mt][nt] = __builtin_amdgcn_mfma_f32_16x16x32_bf16(
                        af, bf[nt], acc[mt][nt], 0, 0, 0);
            }
        }
        __syncthreads();
    }

    const int mBase = mIdx * 256;
    const int nBase = nIdx * 128;
    if (ks == 0) {
        // fused routed bias: out = acc + sum_e rw[row][e]*b3[e][col]
        #pragma unroll
        for (int mt = 0; mt < 8; ++mt) {
            #pragma unroll
            for (int r = 0; r < 4; ++r) {
                const int row = mBase + wm * 128 + mt * 16 + quad * 4 + r;
                const float4 rwa = *(const float4*)(rw + (size_t)row * E_DIM);
                const float4 rwb = *(const float4*)(rw + (size_t)row * E_DIM + 4);
                #pragma unroll
                for (int nt = 0; nt < 4; ++nt) {
                    const int col = nBase + wn * 64 + nt * 16 + cq;
                    float bias = rwa.x * b3[0 * H_DIM + col] + rwa.y * b3[1 * H_DIM + col]
                               + rwa.z * b3[2 * H_DIM + col] + rwa.w * b3[3 * H_DIM + col]
                               + rwb.x * b3[4 * H_DIM + col] + rwb.y * b3[5 * H_DIM + col]
                               + rwb.z * b3[6 * H_DIM + col] + rwb.w * b3[7 * H_DIM + col];
                    out[(size_t)row * H_DIM + col] = acc[mt][nt][r] + bias;
                }
            }
        }
    } else {
        #pragma unroll
        for (int mt = 0; mt < 8; ++mt) {
            #pragma unroll
            for (int r = 0; r < 4; ++r) {
                const int row = mBase + wm * 128 + mt * 16 + quad * 4 + r;
                #pragma unroll
                for (int nt = 0; nt < 4; ++nt) {
                    const int col = nBase + wn * 64 + nt * 16 + cq;
                    p0[(size_t)row * H_DIM + col] = f2bf(acc[mt][nt][r]);
                }
            }
        }
    }
}

// ---------------- launch ----------------

extern "C" void kernel_launch(void* const* d_in, const int* in_sizes, int n_in,
                              void* d_out, int out_size, void* d_ws, size_t ws_size,
                              hipStream_t stream) {
    const float* hs = (const float*)d_in[0];   // [T,H]
    const float* rw = (const float*)d_in[1];   // [T,E]
    const float* w1 = (const float*)d_in[2];   // [E,H,2D]
    const float* b1 = (const float*)d_in[3];   // [E,2D]
    const float* w3 = (const float*)d_in[4];   // [E,D,H]
    const float* b3 = (const float*)d_in[5];   // [E,H]
    float* out = (float*)d_out;

    char* ws = (char*)d_ws;
    unsigned short* hsb   = (unsigned short*)(ws);                          // 16 MB
    unsigned short* w1b   = (unsigned short*)(ws + ((size_t)16 << 20));     // 32 MB
    unsigned short* w3t   = (unsigned short*)(ws + ((size_t)48 << 20));     // 16 MB
    unsigned short* act2t = (unsigned short*)(ws + ((size_t)64 << 20));     // 128 MB
    // bf16 partial reuses hsb region (dead after gemm1): 16 MB
    unsigned short* p0 = (unsigned short*)(ws);

    // 1) hs -> bf16
    {
        size_t n = (size_t)T_DIM * H_DIM;  // 8388608
        f32_to_bf16_kernel<<<dim3(n / (256 * 4)), dim3(256), 0, stream>>>(hs, hsb, n);
    }
    // 2) W1 [E][H][2D] -> w1b [E][2D'][H] bf16 with gate/up 16-col deinterleave
    transpose_conv_kernel<<<dim3(TWO_D / 32, H_DIM / 32, E_DIM), dim3(256), 0, stream>>>(
        w1, w1b, TWO_D, (size_t)H_DIM * TWO_D, (size_t)TWO_D * H_DIM, (size_t)H_DIM, 1);
    // 3) W3 [E][D][H] -> w3t tiled bf16 (XOR chunk swizzle baked in)
    transpose_w3_tiled_kernel<<<dim3(H_DIM / 32, D_DIM / 32, E_DIM), dim3(256), 0, stream>>>(
        w3, w3t);
    // 4) GEMM1 128^2 (proven) + GLU epilogue -> act2t tiled (x=m fastest)
    gemm1_kernel<<<dim3(T_DIM / 128, TWO_D / 128, E_DIM), dim3(256), 0, stream>>>(
        (const short*)hsb, (const short*)w1b, b1, rw, act2t);
    // 5) GEMM2 256x128 split-K=2 (512 blocks = 2/CU): ks0 -> out (+bias), ks1 -> p0
    gemm2_kernel<<<dim3(512), dim3(256), 0, stream>>>(
        (const short*)act2t, (const short*)w3t, rw, b3, out, p0);
    // 6) out += p0
    reduce_kernel<<<dim3(T_DIM), dim3(H_DIM / 4), 0, stream>>>(p0, out);
}

// Round 13
// 563.082 us; speedup vs baseline: 1.1151x; 1.1151x over previous
//
#include <hip/hip_runtime.h>
#include <hip/hip_bf16.h>

// Problem constants: T=8192, H=1024, D=1024, E=8, 2D=2048, K2=E*D=8192
#define T_DIM 8192
#define H_DIM 1024
#define D_DIM 1024
#define E_DIM 8
#define TWO_D 2048
#define K2 8192

#define ALPHA_C 1.702f
#define LIMIT_C 7.0f

typedef __attribute__((ext_vector_type(8))) short s8v;   // 8 bf16 = 4 VGPRs
typedef __attribute__((ext_vector_type(4))) float f4v;   // MFMA accumulator

__device__ __forceinline__ void g2l16(const void* g, void* l) {
    // async global->LDS, 16B per lane; LDS dest = wave-uniform base + lane*16
    __builtin_amdgcn_global_load_lds((const __attribute__((address_space(1))) void*)g,
                                     (__attribute__((address_space(3))) void*)l, 16, 0, 0);
}

__device__ __forceinline__ unsigned short f2bf(float f) {
    __hip_bfloat16 h = __float2bfloat16(f);
    return __builtin_bit_cast(unsigned short, h);
}

// ---------------- convert kernels ----------------

__global__ void f32_to_bf16_kernel(const float* __restrict__ in,
                                   unsigned short* __restrict__ out, size_t n) {
    size_t i = ((size_t)blockIdx.x * blockDim.x + threadIdx.x) * 4;
    if (i + 3 < n) {
        float4 v = *(const float4*)(in + i);
        ushort4 o;
        o.x = f2bf(v.x); o.y = f2bf(v.y); o.z = f2bf(v.z); o.w = f2bf(v.w);
        *(ushort4*)(out + i) = o;
    }
}

// W1 [E][H][2D] -> w1b [E][2D'][H] bf16 with gate/up 16-col deinterleave.
// out[b*obs + remap(c)*ors + r] = bf16(in[b*ibs + r*cols + c]); 32x32 tiles.
__global__ void transpose_conv_kernel(const float* __restrict__ in,
                                      unsigned short* __restrict__ out,
                                      int cols, size_t ibs, size_t obs, size_t ors,
                                      int remap) {
    __shared__ float t[32][33];
    const int b = blockIdx.z;
    const int c0 = blockIdx.x * 32, r0 = blockIdx.y * 32;
    const int tx = threadIdx.x & 31, ty = threadIdx.x >> 5;  // ty in 0..7
    const float* ip = in + (size_t)b * ibs;
    #pragma unroll
    for (int i = 0; i < 4; ++i)
        t[ty + i * 8][tx] = ip[(size_t)(r0 + ty + i * 8) * cols + c0 + tx];
    __syncthreads();
    unsigned short* op = out + (size_t)b * obs;
    #pragma unroll
    for (int i = 0; i < 4; ++i) {
        int c = c0 + ty + i * 8;
        int nc = remap ? ((c & ~31) + ((c & 1) << 4) + ((c >> 1) & 15)) : c;
        op[(size_t)nc * ors + r0 + tx] = f2bf(t[tx][ty + i * 8]);
    }
}

// W3 [E][D][H] -> w3t tiled bf16: tile (nt, kt) = [128 H-rows][64 k-elems], laid out
// at ((nt*128 + kt)*8192), with XOR chunk swizzle baked in: element (hcol, k) goes to
// tile offset (hcol&127)*64 + ((k&63) ^ ((hcol&7)<<3)).  k = e*1024 + d.
__global__ void transpose_w3_tiled_kernel(const float* __restrict__ in,
                                          unsigned short* __restrict__ out) {
    __shared__ float t[32][33];
    const int e = blockIdx.z;
    const int c0 = blockIdx.x * 32;   // H cols
    const int r0 = blockIdx.y * 32;   // D rows
    const int tx = threadIdx.x & 31, ty = threadIdx.x >> 5;
    const float* ip = in + (size_t)e * D_DIM * H_DIM;
    #pragma unroll
    for (int i = 0; i < 4; ++i)
        t[ty + i * 8][tx] = ip[(size_t)(r0 + ty + i * 8) * H_DIM + c0 + tx];
    __syncthreads();
    #pragma unroll
    for (int i = 0; i < 4; ++i) {
        const int hcol = c0 + ty + i * 8;
        const int kk = e * D_DIM + r0 + tx;
        const int nt = hcol >> 7, rIn = hcol & 127;
        const int kt = kk >> 6, c = kk & 63;
        out[((size_t)nt * 128 + kt) * 8192 + rIn * 64 + (c ^ ((rIn & 7) << 3))] =
            f2bf(t[tx][ty + i * 8]);
    }
}

// out[t][h] += p0f (f32 partial from gemm2 ks=1) + sum_e rw[t][e]*b3[e][h]
__global__ void reduce_bias_kernel(const float* __restrict__ p0f,
                                   const float* __restrict__ rw,
                                   const float* __restrict__ b3,
                                   float* __restrict__ out) {
    const int t = blockIdx.x;
    const int h = threadIdx.x * 4;
    const size_t idx = (size_t)t * H_DIM + h;
    float r[E_DIM];
    #pragma unroll
    for (int e = 0; e < E_DIM; ++e) r[e] = rw[(size_t)t * E_DIM + e];
    float4 v = *(const float4*)(out + idx);
    float4 p = *(const float4*)(p0f + idx);
    v.x += p.x; v.y += p.y; v.z += p.z; v.w += p.w;
    #pragma unroll
    for (int e = 0; e < E_DIM; ++e) {
        float4 bb = *(const float4*)(b3 + (size_t)e * H_DIM + h);
        v.x += r[e] * bb.x; v.y += r[e] * bb.y; v.z += r[e] * bb.z; v.w += r[e] * bb.w;
    }
    *(float4*)(out + idx) = v;
}

// ---------------- GEMM1 (proven config: 259-270 µs, MfmaUtil ~51) ----------------
// 128x128 tile, BK=64, 4 waves, single-buffer 32 KB, ~3 blocks/CU.
// gu = hs @ W1[e] + b1[e]; act2 = rw*(up+1)*glu, written TILED+swizzled (act2t).
// A: hsb [T][H] bf16. B: w1b [E][2D'][H] bf16 (deinterleaved B^T).
// Grid (x=m fastest, y=n, z=e): 8 consecutive blocks (8 XCDs) share one B n-tile.

__global__ __launch_bounds__(256, 2) void gemm1_kernel(
    const short* __restrict__ Ag0,      // hsb
    const short* __restrict__ Bg0,      // w1b
    const float* __restrict__ b1,       // [E][2D] original interleaved
    const float* __restrict__ rw,       // [T][E]
    unsigned short* __restrict__ act2t) // tiled [64][128][128][64]
{
    const int e = blockIdx.z;
    const int mBase = blockIdx.x * 128;
    const int nBase = blockIdx.y * 128;
    const int tid = threadIdx.x;
    const int lane = tid & 63;
    const int wave = tid >> 6;
    const int wm = wave >> 1, wn = wave & 1;
    const int cq = lane & 15, quad = lane >> 4;

    __shared__ __align__(16) short As[128 * 64];
    __shared__ __align__(16) short Bs[128 * 64];

    const short* Ag = Ag0 + (size_t)mBase * H_DIM;
    const short* Bg = Bg0 + ((size_t)e * TWO_D + nBase) * H_DIM;

    f4v acc[4][4];
    #pragma unroll
    for (int mt = 0; mt < 4; ++mt)
        #pragma unroll
        for (int nt = 0; nt < 4; ++nt)
            acc[mt][nt] = (f4v){0.f, 0.f, 0.f, 0.f};

    const int srow8 = lane >> 3;                 // 0..7
    const int gco = ((lane & 7) ^ srow8) * 8;    // swizzled global k-offset (elements)
    const int cq7 = cq & 7;

    for (int k0 = 0; k0 < H_DIM; k0 += 64) {
        #pragma unroll
        for (int i = 0; i < 4; ++i) {
            const int r = wave * 32 + i * 8 + srow8;
            g2l16(Ag + (size_t)r * H_DIM + k0 + gco, As + (wave * 32 + i * 8) * 64);
            g2l16(Bg + (size_t)r * H_DIM + k0 + gco, Bs + (wave * 32 + i * 8) * 64);
        }
        __syncthreads();
        #pragma unroll
        for (int h = 0; h < 2; ++h) {
            s8v af[4], bf[4];
            const int pc = (((h << 2) + quad) ^ cq7) * 8;  // phys chunk offset (elements)
            #pragma unroll
            for (int i = 0; i < 4; ++i) {
                af[i] = *(const s8v*)(As + (wm * 64 + i * 16 + cq) * 64 + pc);
                bf[i] = *(const s8v*)(Bs + (wn * 64 + i * 16 + cq) * 64 + pc);
            }
            #pragma unroll
            for (int mt = 0; mt < 4; ++mt)
                #pragma unroll
                for (int nt = 0; nt < 4; ++nt)
                    acc[mt][nt] = __builtin_amdgcn_mfma_f32_16x16x32_bf16(
                        af[mt], bf[nt], acc[mt][nt], 0, 0, 0);
        }
        __syncthreads();
    }

    // epilogue: even nt tile = gate, odd nt tile = up for the same D-cols.
    float rwv[4][4];
    #pragma unroll
    for (int mt = 0; mt < 4; ++mt)
        #pragma unroll
        for (int r = 0; r < 4; ++r)
            rwv[mt][r] = rw[(size_t)(mBase + wm * 64 + mt * 16 + quad * 4 + r) * E_DIM + e];

    const int kt_blk = e * 16 + blockIdx.y;
    unsigned short* tb = act2t + ((size_t)blockIdx.x * 128 + kt_blk) * 8192;

    #pragma unroll
    for (int p = 0; p < 2; ++p) {
        const int j = (((nBase + wn * 64 + p * 32) >> 5) << 4) + cq;   // D-col in [0,1024)
        const float gb = b1[(size_t)e * TWO_D + 2 * j];
        const float ub = b1[(size_t)e * TWO_D + 2 * j + 1];
        const int c = wn * 32 + p * 16 + cq;                           // j & 63
        #pragma unroll
        for (int mt = 0; mt < 4; ++mt) {
            #pragma unroll
            for (int r = 0; r < 4; ++r) {
                float gate = acc[mt][2 * p][r] + gb;
                float up   = acc[mt][2 * p + 1][r] + ub;
                gate = fminf(gate, LIMIT_C);
                up = fminf(fmaxf(up, -LIMIT_C), LIMIT_C);
                float glu = gate / (1.f + __expf(-ALPHA_C * gate));
                float a = (up + 1.f) * glu * rwv[mt][r];
                const int rIn = wm * 64 + mt * 16 + quad * 4 + r;      // row within tile
                tb[rIn * 64 + (c ^ ((rIn & 7) << 3))] = f2bf(a);
            }
        }
    }
}

// ---------------- GEMM2 (r9 best-measured config): 256x128, split-K=2 ----------
// out_partial = act2 @ w3^T. A: act2t tiled [64][128][128][64] bf16 (XOR baked).
// B: w3t tiled [8][128][128][64] bf16. Grid 512 = 32m x 8n x 2ks = 2 blocks/CU.
// id: m = id&31 (8 n-sharers of an A panel have same id%8 -> same XCD L2),
// n = (id>>5)&7, ks = id>>8 (K-slice of 4096 = 64 BK steps).
// Staging fully contiguous: each g2l16 = 1 KB (8 rows x 64 elems) at src+lane*16B.
// ks0 -> out (raw f32), ks1 -> p0f (f32); reduce adds partial + routed bias.

__global__ __launch_bounds__(256, 2) void gemm2_kernel(
    const short* __restrict__ At,      // act2t
    const short* __restrict__ Bt,      // w3t
    float* __restrict__ out,           // [T][H] raw acc (ks=0)
    float* __restrict__ p0f)           // [T][H] f32 partial (ks=1)
{
    const int id = blockIdx.x;
    const int mIdx = id & 31;
    const int nIdx = (id >> 5) & 7;
    const int ks = id >> 8;
    const int tid = threadIdx.x;
    const int lane = tid & 63;
    const int wave = tid >> 6;           // 0..3
    const int wm = wave >> 1, wn = wave & 1;
    const int cq = lane & 15, quad = lane >> 4;
    const int cq7 = cq & 7;
    const int lane8 = lane * 8;

    __shared__ __align__(16) short As[256 * 64];   // 32 KiB
    __shared__ __align__(16) short Bs[128 * 64];   // 16 KiB

    f4v acc[8][4];
    #pragma unroll
    for (int mt = 0; mt < 8; ++mt)
        #pragma unroll
        for (int nt = 0; nt < 4; ++nt)
            acc[mt][nt] = (f4v){0.f, 0.f, 0.f, 0.f};

    #pragma unroll 1
    for (int s = 0; s < 64; ++s) {
        const int kt = ks * 64 + s;
        #pragma unroll
        for (int i = 0; i < 8; ++i) {
            const int R = i * 32 + wave * 8;
            const short* src = At +
                ((size_t)(2 * mIdx + (R >> 7)) * 128 + kt) * 8192 + (R & 127) * 64 + lane8;
            g2l16(src, As + R * 64);
        }
        #pragma unroll
        for (int i = 0; i < 4; ++i) {
            const int R = i * 32 + wave * 8;
            const short* src = Bt + ((size_t)nIdx * 128 + kt) * 8192 + R * 64 + lane8;
            g2l16(src, Bs + R * 64);
        }
        __syncthreads();
        #pragma unroll
        for (int h = 0; h < 2; ++h) {
            const int pc = (((h << 2) + quad) ^ cq7) * 8;
            s8v bf[4];
            #pragma unroll
            for (int i = 0; i < 4; ++i)
                bf[i] = *(const s8v*)(Bs + (wn * 64 + i * 16 + cq) * 64 + pc);
            #pragma unroll
            for (int mt = 0; mt < 8; ++mt) {
                const s8v af = *(const s8v*)(As + (wm * 128 + mt * 16 + cq) * 64 + pc);
                #pragma unroll
                for (int nt = 0; nt < 4; ++nt)
                    acc[mt][nt] = __builtin_amdgcn_mfma_f32_16x16x32_bf16(
                        af, bf[nt], acc[mt][nt], 0, 0, 0);
            }
        }
        __syncthreads();
    }

    float* dst = (ks == 0) ? out : p0f;
    const int mBase = mIdx * 256;
    const int nBase = nIdx * 128;
    #pragma unroll
    for (int mt = 0; mt < 8; ++mt) {
        #pragma unroll
        for (int r = 0; r < 4; ++r) {
            const int row = mBase + wm * 128 + mt * 16 + quad * 4 + r;
            #pragma unroll
            for (int nt = 0; nt < 4; ++nt) {
                const int col = nBase + wn * 64 + nt * 16 + cq;
                dst[(size_t)row * H_DIM + col] = acc[mt][nt][r];
            }
        }
    }
}

// ---------------- launch ----------------

extern "C" void kernel_launch(void* const* d_in, const int* in_sizes, int n_in,
                              void* d_out, int out_size, void* d_ws, size_t ws_size,
                              hipStream_t stream) {
    const float* hs = (const float*)d_in[0];   // [T,H]
    const float* rw = (const float*)d_in[1];   // [T,E]
    const float* w1 = (const float*)d_in[2];   // [E,H,2D]
    const float* b1 = (const float*)d_in[3];   // [E,2D]
    const float* w3 = (const float*)d_in[4];   // [E,D,H]
    const float* b3 = (const float*)d_in[5];   // [E,H]
    float* out = (float*)d_out;

    char* ws = (char*)d_ws;
    unsigned short* hsb   = (unsigned short*)(ws);                          // 16 MB
    unsigned short* w1b   = (unsigned short*)(ws + ((size_t)16 << 20));     // 32 MB
    unsigned short* w3t   = (unsigned short*)(ws + ((size_t)48 << 20));     // 16 MB
    unsigned short* act2t = (unsigned short*)(ws + ((size_t)64 << 20));     // 128 MB
    // f32 partial reuses hsb+w1b region (dead after gemm1): 32 MB
    float* p0f = (float*)(ws);

    // 1) hs -> bf16
    {
        size_t n = (size_t)T_DIM * H_DIM;  // 8388608
        f32_to_bf16_kernel<<<dim3(n / (256 * 4)), dim3(256), 0, stream>>>(hs, hsb, n);
    }
    // 2) W1 [E][H][2D] -> w1b [E][2D'][H] bf16 with gate/up 16-col deinterleave
    transpose_conv_kernel<<<dim3(TWO_D / 32, H_DIM / 32, E_DIM), dim3(256), 0, stream>>>(
        w1, w1b, TWO_D, (size_t)H_DIM * TWO_D, (size_t)TWO_D * H_DIM, (size_t)H_DIM, 1);
    // 3) W3 [E][D][H] -> w3t tiled bf16 (XOR chunk swizzle baked in)
    transpose_w3_tiled_kernel<<<dim3(H_DIM / 32, D_DIM / 32, E_DIM), dim3(256), 0, stream>>>(
        w3, w3t);
    // 4) GEMM1 128^2 (proven) + GLU epilogue -> act2t tiled (x=m fastest)
    gemm1_kernel<<<dim3(T_DIM / 128, TWO_D / 128, E_DIM), dim3(256), 0, stream>>>(
        (const short*)hsb, (const short*)w1b, b1, rw, act2t);
    // 5) GEMM2 256x128 split-K=2 (512 blocks = 2/CU): ks0 -> out, ks1 -> p0f
    gemm2_kernel<<<dim3(512), dim3(256), 0, stream>>>(
        (const short*)act2t, (const short*)w3t, out, p0f);
    // 6) out += p0f + sum_e rw*b3
    reduce_bias_kernel<<<dim3(T_DIM), dim3(H_DIM / 4), 0, stream>>>(
        p0f, rw, b3, out);
}